// Round 17
// baseline (11.964 us; speedup 1.0000x reference)
//
#include <hip/hip_runtime.h>

// Euler characteristic curve of sublevel cubical complex.
// x: [B,C,H,W] f32 -> out: [B,C,RES] f32.
//
// R15 single-kernel structure (proven 11.6us) + two composable changes:
//   1) launch_bounds(512,4): grid 512 = exactly 2 blocks/CU (grid-limited),
//      so relaxing the VGPR cap 85 -> 128 costs zero occupancy.
//   2) FULL load hoist: all 18 loads (9 float4 rows + 9 right-halo scalars,
//      address-independent) issued upfront -> one vmem-latency wait total,
//      instead of 8x depth-1 prefetch stalls (compute/iter ~150cyc < L3
//      latency ~300-600cyc). R8 measured full-hoist > rolling at RPT=4.
//   - R9-proven inner loop: branchless 4 ds_add per vertex into
//     hist[bin][col] int32 x 32 cols (8 KiB; 2 lanes/bank = free aliasing);
//     edge/face bins via integer max (bin monotone: bin(max)=max(bin)).
//   - epilogue: 512-thread rotated conflict-free reduce, 64-lane shfl
//     inclusive scan, direct store. One dispatch, no ws, no fill node.

#define HH 128
#define WW 128
#define RESB 64
#define NT 512
#define RPT 8            // rows per thread
#define BC 512           // one block per image

__device__ __forceinline__ int binq(float F) {
    // F in [0,1): ceil(F*63) lands in [0,63] -- no clamps needed.
    return (int)ceilf(F * 63.0f);
}

__global__ __launch_bounds__(NT, 4) void ecc_fused(const float* __restrict__ X,
                                                   float* __restrict__ out) {
    __shared__ int hist[RESB * 32];  // [bin][col], 8 KiB
    const int bc = blockIdx.x;
    const int tid = threadIdx.x;
    const int ln = tid & 31;  // lane column
    const float* __restrict__ x = X + (size_t)bc * (HH * WW);

    ((int4*)hist)[tid] = make_int4(0, 0, 0, 0);  // 2048 dwords / 512 threads
    __syncthreads();

    const int col4 = tid & 31;   // which float4 of the row
    const int rg = tid >> 5;     // 0..15 row group
    const int r0 = rg * RPT;
    const int c0 = col4 * 4;
    const int cR = (col4 < 31) ? c0 + 4 : WW - 1;  // right halo col (k=3 masked)

    // All 18 loads upfront -- address-independent, one latency wait.
    float4 A[RPT + 1];
    float Hs[RPT + 1];
#pragma unroll
    for (int j = 0; j <= RPT; ++j) {
        const int rr = (r0 + j < HH) ? r0 + j : HH - 1;  // clamp (rg=15 masked)
        A[j] = *(const float4*)(x + rr * WW + c0);
        Hs[j] = x[rr * WW + cR];
    }

    int bn[RPT + 1][5];
#pragma unroll
    for (int j = 0; j <= RPT; ++j) {
        bn[j][0] = binq(A[j].x); bn[j][1] = binq(A[j].y);
        bn[j][2] = binq(A[j].z); bn[j][3] = binq(A[j].w);
        bn[j][4] = binq(Hs[j]);
    }

#pragma unroll
    for (int dr = 0; dr < RPT; ++dr) {
        // hD folds to 1 for dr<7; last thread-row (rg=15, row 127) masked.
        const int hD = (dr < RPT - 1) ? 1 : ((rg < 15) ? 1 : 0);
#pragma unroll
        for (int k = 0; k < 4; ++k) {
            const int hR = (k < 3) ? 1 : ((col4 < 31) ? 1 : 0);  // folds for k<3
            const int u00 = bn[dr][k];
            const int bh  = max(u00, bn[dr][k + 1]);
            const int bvv = max(u00, bn[dr + 1][k]);
            const int bf  = max(bh, max(bn[dr + 1][k], bn[dr + 1][k + 1]));
            atomicAdd(&hist[(u00 << 5) + ln], 1);          // vertex +
            atomicAdd(&hist[(bh  << 5) + ln], -hR);        // h-edge -
            atomicAdd(&hist[(bvv << 5) + ln], -hD);        // v-edge -
            atomicAdd(&hist[(bf  << 5) + ln], hR & hD);    // face  +
        }
    }
    __syncthreads();

    // Reduce over 32 columns: thread (bin = tid&63, q = tid>>6 in 0..7) sums 4,
    // rotated -> all 32 banks covered, 2 lanes/bank = free.
    const int bin = tid & 63;
    const int q = tid >> 6;
    int ssum = 0;
#pragma unroll
    for (int k = 0; k < 4; ++k) {
        ssum += hist[(bin << 5) + ((q * 4 + bin + k) & 31)];
    }
    __syncthreads();
    hist[tid] = ssum;  // partial at [q*64 + bin]
    __syncthreads();
    if (tid < RESB) {
        int vv = 0;
#pragma unroll
        for (int qq = 0; qq < 8; ++qq) vv += hist[qq * 64 + tid];
        // Inclusive prefix scan across 64 lanes (= bins) -> cumsum.
#pragma unroll
        for (int d = 1; d < 64; d <<= 1) {
            const int up = __shfl_up(vv, d, 64);
            if (tid >= d) vv += up;
        }
        out[bc * RESB + tid] = (float)vv;
    }
}

extern "C" void kernel_launch(void* const* d_in, const int* in_sizes, int n_in,
                              void* d_out, int out_size, void* d_ws, size_t ws_size,
                              hipStream_t stream) {
    const float* x = (const float*)d_in[0];
    float* out = (float*)d_out;
    ecc_fused<<<BC, NT, 0, stream>>>(x, out);
}

// Round 18
// 11.544 us; speedup vs baseline: 1.0364x; 1.0364x over previous
//
#include <hip/hip_runtime.h>

// Euler characteristic curve of sublevel cubical complex.
// x: [B,C,H,W] f32 -> out: [B,C,RES] f32.
//
// R15 structure (proven 11.6us), single change: bins carried as LDS BYTE
// ADDRESSES. binq returns (bin<<7) + ln*4 (lane column folded in at convert
// time). All thread-local bin values share the same additive ln*4 < 128, so
// integer max() on addresses == address of bin-max (monotone). The 4
// per-atomic v_lshl_add address ops vanish (45 fused lshl_adds at convert
// replace 128 per-atomic ones) -> ~3.5 fewer VALU per vertex on the issue
// stream the LDS+VALU pipes share.
//   - one 512-thread block per image; 8 rows/thread, depth-1 prefetch;
//     branchless 4 ds_add per vertex; hist[bin][col] int32 x 32 (8 KiB);
//     rotated conflict-free reduce; 64-lane shfl scan; direct store.
//   - launch_bounds(512,6) (R15-proven).

#define HH 128
#define WW 128
#define RESB 64
#define NT 512
#define RPT 8            // rows per thread
#define BC 512           // one block per image

__global__ __launch_bounds__(NT, 6) void ecc_fused(const float* __restrict__ X,
                                                   float* __restrict__ out) {
    __shared__ int hist[RESB * 32];  // [bin][col], 8 KiB
    const int bc = blockIdx.x;
    const int tid = threadIdx.x;
    const int lnb = (tid & 31) << 2;  // lane-column byte offset, < 128
    const float* __restrict__ x = X + (size_t)bc * (HH * WW);

    ((int4*)hist)[tid] = make_int4(0, 0, 0, 0);  // 2048 dwords / 512 threads
    __syncthreads();

    // binq as byte address: (ceil(F*63) << 7) + lnb.  F in [0,1) -> bin 0..63.
    auto binqa = [lnb](float F) {
        return ((int)ceilf(F * 63.0f) << 7) + lnb;
    };
    char* const hb = (char*)hist;

    const int col4 = tid & 31;   // which float4 of the row
    const int rg = tid >> 5;     // 0..15 row group
    const int r0 = rg * RPT;
    const int c0 = col4 * 4;
    const int cR = (col4 < 31) ? c0 + 4 : WW - 1;  // right halo col (k=3 masked)

    int u[5], v[5], w[5];
    {
        const float4 a = *(const float4*)(x + r0 * WW + c0);
        const float aR = x[r0 * WW + cR];
        u[0] = binqa(a.x); u[1] = binqa(a.y); u[2] = binqa(a.z); u[3] = binqa(a.w); u[4] = binqa(aR);
        const float4 b = *(const float4*)(x + (r0 + 1) * WW + c0);
        const float bR = x[(r0 + 1) * WW + cR];
        v[0] = binqa(b.x); v[1] = binqa(b.y); v[2] = binqa(b.z); v[3] = binqa(b.w); v[4] = binqa(bR);
    }

#pragma unroll
    for (int dr = 0; dr < RPT; ++dr) {
        // hD folds to 1 for dr<7; last thread-row (rg=15, row 127) masked.
        const int hD = (dr < RPT - 1) ? 1 : ((rg < 15) ? 1 : 0);
        // Prefetch row r0+dr+2 (clamped) BEFORE compute -> load lands under it.
        float4 p4; float pR;
        if (dr < RPT - 1) {
            const int rn = (r0 + dr + 2 < HH) ? r0 + dr + 2 : HH - 1;
            p4 = *(const float4*)(x + rn * WW + c0);
            pR = x[rn * WW + cR];
        }
#pragma unroll
        for (int k = 0; k < 4; ++k) {
            const int hR = (k < 3) ? 1 : ((col4 < 31) ? 1 : 0);  // folds for k<3
            const int u00 = u[k];
            const int bh  = max(u00, u[k + 1]);
            const int bvv = max(u00, v[k]);
            const int bf  = max(bh, max(v[k], v[k + 1]));
            atomicAdd((int*)(hb + u00), 1);          // vertex +
            atomicAdd((int*)(hb + bh),  -hR);        // h-edge -
            atomicAdd((int*)(hb + bvv), -hD);        // v-edge -
            atomicAdd((int*)(hb + bf),  hR & hD);    // face  +
        }
        if (dr < RPT - 1) {
            w[0] = binqa(p4.x); w[1] = binqa(p4.y); w[2] = binqa(p4.z); w[3] = binqa(p4.w); w[4] = binqa(pR);
#pragma unroll
            for (int k = 0; k < 5; ++k) { u[k] = v[k]; v[k] = w[k]; }
        }
    }
    __syncthreads();

    // Reduce over 32 columns: thread (bin = tid&63, q = tid>>6 in 0..7) sums 4,
    // rotated -> all 32 banks covered, 2 lanes/bank = free.
    const int bin = tid & 63;
    const int q = tid >> 6;
    int ssum = 0;
#pragma unroll
    for (int k = 0; k < 4; ++k) {
        ssum += hist[(bin << 5) + ((q * 4 + bin + k) & 31)];
    }
    __syncthreads();
    hist[tid] = ssum;  // partial at [q*64 + bin]
    __syncthreads();
    if (tid < RESB) {
        int vv = 0;
#pragma unroll
        for (int qq = 0; qq < 8; ++qq) vv += hist[qq * 64 + tid];
        // Inclusive prefix scan across 64 lanes (= bins) -> cumsum.
#pragma unroll
        for (int d = 1; d < 64; d <<= 1) {
            const int up = __shfl_up(vv, d, 64);
            if (tid >= d) vv += up;
        }
        out[bc * RESB + tid] = (float)vv;
    }
}

extern "C" void kernel_launch(void* const* d_in, const int* in_sizes, int n_in,
                              void* d_out, int out_size, void* d_ws, size_t ws_size,
                              hipStream_t stream) {
    const float* x = (const float*)d_in[0];
    float* out = (float*)d_out;
    ecc_fused<<<BC, NT, 0, stream>>>(x, out);
}